// Round 1
// baseline (730.558 us; speedup 1.0000x reference)
//
#include <hip/hip_runtime.h>
#include <cstddef>

#define B_ 16
#define N_ 4096
#define D_ 256
#define EPS_ 1e-6f

__device__ __forceinline__ float sigmoidf_(float x) {
    return 1.0f / (1.0f + __expf(-x));
}

// ---------------------------------------------------------------------------
// phi GEMM: out[row, e] = sigmoid(sum_d X[row,d]*W[d,e] + bias[e])
// rows = B*N (65536), K = D = 256, cols = D = 256.
// Optionally accumulates rowsum[row] (sum over e) and per-batch
// colsum[b*D+e] (sum over n within batch). 64x64 tile, 4x4 micro, BK=32.
// ---------------------------------------------------------------------------
__global__ __launch_bounds__(256) void phi_gemm_kernel(
    const float* __restrict__ X, const float* __restrict__ W,
    const float* __restrict__ bias, float* __restrict__ out,
    float* __restrict__ rowsum, float* __restrict__ colsum)
{
    __shared__ float As[32][68];   // [k][row] (transposed store, +4 pad keeps 16B align)
    __shared__ float Bs[32][68];   // [k][col]
    __shared__ float redRow[64];
    __shared__ float redCol[64];

    const int t  = threadIdx.x;
    const int tx = t & 15, ty = t >> 4;
    const int row0 = blockIdx.x * 64;
    const int c0   = blockIdx.y * 64;

    const int la_c = t & 31;   // k index for A load
    const int la_r = t >> 5;   // row base (stride 8)
    const int lb_c = t & 63;   // col index for B load
    const int lb_r = t >> 6;   // k base (stride 4)

    float acc[4][4] = {};

    for (int k0 = 0; k0 < D_; k0 += 32) {
        #pragma unroll
        for (int i = 0; i < 8; i++) {
            int r = la_r + 8 * i;
            As[la_c][r] = X[(size_t)(row0 + r) * D_ + k0 + la_c];
        }
        #pragma unroll
        for (int i = 0; i < 8; i++) {
            int r = lb_r + 4 * i;
            Bs[r][lb_c] = W[(size_t)(k0 + r) * D_ + c0 + lb_c];
        }
        __syncthreads();
        #pragma unroll
        for (int k = 0; k < 32; k++) {
            float4 a  = *reinterpret_cast<const float4*>(&As[k][ty * 4]);
            float4 bv = *reinterpret_cast<const float4*>(&Bs[k][tx * 4]);
            float av[4] = {a.x, a.y, a.z, a.w};
            float bb[4] = {bv.x, bv.y, bv.z, bv.w};
            #pragma unroll
            for (int i = 0; i < 4; i++)
                #pragma unroll
                for (int j = 0; j < 4; j++)
                    acc[i][j] += av[i] * bb[j];
        }
        __syncthreads();
    }

    float phi[4][4];
    #pragma unroll
    for (int j = 0; j < 4; j++) {
        float be = bias[c0 + tx * 4 + j];
        #pragma unroll
        for (int i = 0; i < 4; i++)
            phi[i][j] = sigmoidf_(acc[i][j] + be);
    }
    #pragma unroll
    for (int i = 0; i < 4; i++) {
        int row = row0 + ty * 4 + i;
        float4 st = {phi[i][0], phi[i][1], phi[i][2], phi[i][3]};
        *reinterpret_cast<float4*>(&out[(size_t)row * D_ + c0 + tx * 4]) = st;
    }

    if (rowsum != nullptr) {
        if (t < 64) redRow[t] = 0.0f;
        __syncthreads();
        #pragma unroll
        for (int i = 0; i < 4; i++) {
            float s = phi[i][0] + phi[i][1] + phi[i][2] + phi[i][3];
            atomicAdd(&redRow[ty * 4 + i], s);
        }
        __syncthreads();
        if (t < 64) atomicAdd(&rowsum[row0 + t], redRow[t]);
    }
    if (colsum != nullptr) {
        if (t < 64) redCol[t] = 0.0f;
        __syncthreads();
        #pragma unroll
        for (int j = 0; j < 4; j++) {
            float s = phi[0][j] + phi[1][j] + phi[2][j] + phi[3][j];
            atomicAdd(&redCol[tx * 4 + j], s);
        }
        __syncthreads();
        const int b = row0 / N_;   // 64-row tiles never straddle a batch
        if (t < 64) atomicAdd(&colsum[b * D_ + c0 + t], redCol[t]);
    }
}

// ---------------------------------------------------------------------------
// softmax denominator over sequence dim:
// denom[b,e] = sum_n exp(phi_k[b,n,e] * V[b,n,e] / (colsum[b,e]+eps))
// |O*V| <= ~5/2048 so no max-subtraction needed.
// ---------------------------------------------------------------------------
__global__ __launch_bounds__(256) void denom_kernel(
    const float* __restrict__ phi_k, const float* __restrict__ V,
    const float* __restrict__ colsum, float* __restrict__ denom)
{
    const int b  = blockIdx.x;
    const int n0 = blockIdx.y * 256;
    const int e  = threadIdx.x;
    const float inv = 1.0f / (colsum[b * D_ + e] + EPS_);
    size_t base = ((size_t)b * N_ + n0) * D_ + e;
    float s = 0.0f;
    for (int n = 0; n < 256; n++) {
        float x = phi_k[base + (size_t)n * D_];
        float v = V[base + (size_t)n * D_];
        s += __expf(x * inv * v);
    }
    atomicAdd(&denom[b * D_ + e], s);
}

// ---------------------------------------------------------------------------
// KV[b,d,e] = (1/denom[b,e]) * sum_n phi_k[b,n,d] * exp(phi_k[b,n,e]*inv_cs[e]*V[b,n,e])
// 64x64 output tile, N split into 4 chunks of 1024 (atomic accumulate) for occupancy.
// ---------------------------------------------------------------------------
__global__ __launch_bounds__(256) void kv_gemm_kernel(
    const float* __restrict__ phi_k, const float* __restrict__ V,
    const float* __restrict__ colsum, const float* __restrict__ denom,
    float* __restrict__ KV)
{
    __shared__ float Ad[32][68];   // [k(n)][d]
    __shared__ float Be[32][68];   // [k(n)][e] = exp term

    const int t  = threadIdx.x;
    const int tx = t & 15, ty = t >> 4;
    const int d0 = blockIdx.x * 64;
    const int e0 = blockIdx.y * 64;
    const int b  = blockIdx.z >> 2;
    const int nc = blockIdx.z & 3;

    const int lc = t & 63;
    const int lr = t >> 6;
    const size_t basebn = (size_t)b * N_;

    const float inv_cs = 1.0f / (colsum[b * D_ + e0 + lc] + EPS_);

    float acc[4][4] = {};
    const int nend = nc * 1024 + 1024;
    for (int n0 = nc * 1024; n0 < nend; n0 += 32) {
        #pragma unroll
        for (int i = 0; i < 8; i++) {
            int k = lr + 4 * i;
            size_t g = (basebn + n0 + k) * (size_t)D_;
            Ad[k][lc] = phi_k[g + d0 + lc];
            float pk  = phi_k[g + e0 + lc];
            float v   = V[g + e0 + lc];
            Be[k][lc] = __expf(pk * inv_cs * v);
        }
        __syncthreads();
        #pragma unroll
        for (int k = 0; k < 32; k++) {
            float4 a  = *reinterpret_cast<const float4*>(&Ad[k][ty * 4]);
            float4 bv = *reinterpret_cast<const float4*>(&Be[k][tx * 4]);
            float av[4] = {a.x, a.y, a.z, a.w};
            float bb[4] = {bv.x, bv.y, bv.z, bv.w};
            #pragma unroll
            for (int i = 0; i < 4; i++)
                #pragma unroll
                for (int j = 0; j < 4; j++)
                    acc[i][j] += av[i] * bb[j];
        }
        __syncthreads();
    }

    float invdn[4];
    #pragma unroll
    for (int j = 0; j < 4; j++)
        invdn[j] = 1.0f / denom[b * D_ + e0 + tx * 4 + j];
    #pragma unroll
    for (int i = 0; i < 4; i++)
        #pragma unroll
        for (int j = 0; j < 4; j++)
            atomicAdd(&KV[((size_t)b * D_ + d0 + ty * 4 + i) * D_ + e0 + tx * 4 + j],
                      acc[i][j] * invdn[j]);
}

// ---------------------------------------------------------------------------
// out[b,n,e] = sigmoid(rs)/(rs+eps) * sum_d phi_q[b,n,d] * KV[b,d,e]
// ---------------------------------------------------------------------------
__global__ __launch_bounds__(256) void out_gemm_kernel(
    const float* __restrict__ phi_q, const float* __restrict__ KV,
    const float* __restrict__ rowsum, float* __restrict__ out)
{
    __shared__ float As[32][68];   // [k(d)][n] transposed
    __shared__ float Bs[32][68];   // [k(d)][e]

    const int t  = threadIdx.x;
    const int tx = t & 15, ty = t >> 4;
    const int n0 = blockIdx.x * 64;
    const int e0 = blockIdx.y * 64;
    const int b  = blockIdx.z;

    const float* A  = phi_q + (size_t)b * N_ * D_;
    const float* Bm = KV    + (size_t)b * D_ * D_;

    const int la_c = t & 31;
    const int la_r = t >> 5;
    const int lb_c = t & 63;
    const int lb_r = t >> 6;

    float acc[4][4] = {};
    for (int k0 = 0; k0 < D_; k0 += 32) {
        #pragma unroll
        for (int i = 0; i < 8; i++) {
            int r = la_r + 8 * i;
            As[la_c][r] = A[(size_t)(n0 + r) * D_ + k0 + la_c];
        }
        #pragma unroll
        for (int i = 0; i < 8; i++) {
            int r = lb_r + 4 * i;
            Bs[r][lb_c] = Bm[(size_t)(k0 + r) * D_ + e0 + lb_c];
        }
        __syncthreads();
        #pragma unroll
        for (int k = 0; k < 32; k++) {
            float4 a  = *reinterpret_cast<const float4*>(&As[k][ty * 4]);
            float4 bv = *reinterpret_cast<const float4*>(&Bs[k][tx * 4]);
            float av[4] = {a.x, a.y, a.z, a.w};
            float bb[4] = {bv.x, bv.y, bv.z, bv.w};
            #pragma unroll
            for (int i = 0; i < 4; i++)
                #pragma unroll
                for (int j = 0; j < 4; j++)
                    acc[i][j] += av[i] * bb[j];
        }
        __syncthreads();
    }

    #pragma unroll
    for (int i = 0; i < 4; i++) {
        int row = n0 + ty * 4 + i;
        float rs   = rowsum[b * N_ + row];
        float gate = sigmoidf_(rs) / (rs + EPS_);
        float4 st = {gate * acc[i][0], gate * acc[i][1],
                     gate * acc[i][2], gate * acc[i][3]};
        *reinterpret_cast<float4*>(
            &out[((size_t)b * N_ + row) * D_ + e0 + tx * 4]) = st;
    }
}

extern "C" void kernel_launch(void* const* d_in, const int* in_sizes, int n_in,
                              void* d_out, int out_size, void* d_ws, size_t ws_size,
                              hipStream_t stream) {
    const float* Q  = (const float*)d_in[0];
    const float* K  = (const float*)d_in[1];
    const float* V  = (const float*)d_in[2];
    const float* Wq = (const float*)d_in[3];
    const float* bq = (const float*)d_in[4];
    const float* Wk = (const float*)d_in[5];
    const float* bk = (const float*)d_in[6];
    float* out = (float*)d_out;
    float* ws  = (float*)d_ws;

    const size_t BND = (size_t)B_ * N_ * D_;
    float* phi_q    = ws;                       // B*N*D
    float* phi_k    = ws + BND;                 // B*N*D
    float* colsum_k = ws + 2 * BND;             // B*D
    float* rowsum_q = colsum_k + B_ * D_;       // B*N
    float* denom    = rowsum_q + (size_t)B_ * N_; // B*D
    float* KV       = denom + B_ * D_;          // B*D*D

    // zero the atomic-accumulated buffers (colsum_k..KV are contiguous)
    size_t zero_floats = (size_t)B_ * D_ + (size_t)B_ * N_ + (size_t)B_ * D_
                       + (size_t)B_ * D_ * D_;
    hipMemsetAsync(colsum_k, 0, zero_floats * sizeof(float), stream);

    dim3 blk(256);
    // phi_k = sigmoid(K@Wk+bk), per-batch column sums
    phi_gemm_kernel<<<dim3(1024, 4), blk, 0, stream>>>(K, Wk, bk, phi_k, nullptr, colsum_k);
    // phi_q = sigmoid(Q@Wq+bq), row sums
    phi_gemm_kernel<<<dim3(1024, 4), blk, 0, stream>>>(Q, Wq, bq, phi_q, rowsum_q, nullptr);
    // softmax denominators over sequence dim
    denom_kernel<<<dim3(B_, N_ / 256), blk, 0, stream>>>(phi_k, V, colsum_k, denom);
    // KV state (exp fused, N split 4-way, atomic accumulate)
    kv_gemm_kernel<<<dim3(D_ / 64, D_ / 64, B_ * 4), blk, 0, stream>>>(
        phi_k, V, colsum_k, denom, KV);
    // final: gate * phi_q @ KV
    out_gemm_kernel<<<dim3(N_ / 64, D_ / 64, B_), blk, 0, stream>>>(
        phi_q, KV, rowsum_q, out);
}

// Round 2
// 331.594 us; speedup vs baseline: 2.2032x; 2.2032x over previous
//
#include <hip/hip_runtime.h>
#include <cstddef>

#define EPS_ 1e-6f

typedef unsigned short u16;
typedef __attribute__((ext_vector_type(8))) short short8;      // bf16x8 MFMA frag
typedef __attribute__((ext_vector_type(8))) unsigned short us8;
typedef __attribute__((ext_vector_type(4))) unsigned short us4;
typedef __attribute__((ext_vector_type(4))) float f32x4;

__device__ __forceinline__ float sigmoidf_(float x){ return 1.0f/(1.0f+__expf(-x)); }
__device__ __forceinline__ u16 f2bf(float x){
  union { float f; unsigned i; } c; c.f = x;
  unsigned r = c.i + 0x7FFFu + ((c.i >> 16) & 1u);   // RNE
  return (u16)(r >> 16);
}
__device__ __forceinline__ float bf2f(u16 u){
  union { unsigned i; float f; } c; c.i = ((unsigned)u) << 16; return c.f;
}

// ---------------------------------------------------------------------------
// WT[e][d] = bf16(W[d][e])  (one block per output row; W is tiny & L2-hot)
// ---------------------------------------------------------------------------
__global__ __launch_bounds__(256) void prep_w(const float* __restrict__ Wq,
                                              const float* __restrict__ Wk,
                                              u16* __restrict__ WqT,
                                              u16* __restrict__ WkT){
  const int e = blockIdx.x & 255;
  const float* W = (blockIdx.x < 256) ? Wq : Wk;
  u16* WT = (blockIdx.x < 256) ? WqT : WkT;
  const int d = threadIdx.x;
  WT[e*256 + d] = f2bf(W[d*256 + e]);
}

// ---------------------------------------------------------------------------
// phi GEMM (bf16 MFMA): phi = sigmoid(X @ W + b), X f32 [65536,256], WT bf16 [e][d].
// Block tile 128(rows) x 128(f), 4 waves (64x64 each), BK=32.
// !TRANS: out = phi bf16 [row][f]; sums = rowsum[row] (atomic).
//  TRANS: out = phi^T bf16 [b][f][n]; sums = colsum[b*256+f] (atomic).
// MFMA layouts (m89/m91-verified): A[m=l&15][k=(l>>4)*8+j], B[k][n=l&15],
// D row=(l>>4)*4+r, col=l&15.
// ---------------------------------------------------------------------------
template<bool TRANS>
__global__ __launch_bounds__(256) void phi_gemm(const float* __restrict__ X,
    const u16* __restrict__ WT, const float* __restrict__ bias,
    u16* __restrict__ outp, float* __restrict__ sums)
{
  __shared__ u16 A_lds[128][40];                 // [n][k], stride 80 B (16B mult)
  __shared__ u16 B_lds[128][40];                 // [f][k]
  __shared__ u16 T_lds[TRANS ? 128*136 : 2];     // transpose buffer [f][n]

  const int t = threadIdx.x;
  const int l = t & 63;
  const int w = t >> 6;
  const int wm = w & 1, wf = w >> 1;
  const int row0 = blockIdx.x * 128;
  const int f0   = blockIdx.y * 128;

  f32x4 acc[4][4];
  #pragma unroll
  for (int i=0;i<4;i++)
    #pragma unroll
    for (int j=0;j<4;j++) acc[i][j] = (f32x4){0.f,0.f,0.f,0.f};

  const int kq = t & 7, nsub = t >> 3;   // A staging: float4 per lane
  const int fr = t >> 2, fq = t & 3;     // B staging: 4 lanes/row, 64B rows
  const int kof = (l >> 4) * 8;

  for (int k0 = 0; k0 < 256; k0 += 32) {
    #pragma unroll
    for (int p = 0; p < 4; p++) {
      int n = p*32 + nsub;
      float4 v = *(const float4*)&X[(size_t)(row0+n)*256 + k0 + kq*4];
      us4 h; h[0]=f2bf(v.x); h[1]=f2bf(v.y); h[2]=f2bf(v.z); h[3]=f2bf(v.w);
      *(us4*)&A_lds[n][kq*4] = h;
    }
    #pragma unroll
    for (int p = 0; p < 2; p++) {
      int f = p*64 + fr;
      *(us8*)&B_lds[f][fq*8] = *(const us8*)&WT[(size_t)(f0+f)*256 + k0 + fq*8];
    }
    __syncthreads();
    short8 af[4], bfr[4];
    #pragma unroll
    for (int mi=0;mi<4;mi++) af[mi]  = *(const short8*)&A_lds[wm*64 + mi*16 + (l&15)][kof];
    #pragma unroll
    for (int fi=0;fi<4;fi++) bfr[fi] = *(const short8*)&B_lds[wf*64 + fi*16 + (l&15)][kof];
    #pragma unroll
    for (int mi=0;mi<4;mi++)
      #pragma unroll
      for (int fi=0;fi<4;fi++)
        acc[mi][fi] = __builtin_amdgcn_mfma_f32_16x16x32_bf16(af[mi], bfr[fi], acc[mi][fi], 0,0,0);
    __syncthreads();
  }

  float bfv[4];
  #pragma unroll
  for (int fi=0;fi<4;fi++) bfv[fi] = bias[f0 + wf*64 + fi*16 + (l&15)];

  if (!TRANS) {
    #pragma unroll
    for (int mi=0;mi<4;mi++) {
      float ph[4][4];
      #pragma unroll
      for (int fi=0;fi<4;fi++)
        #pragma unroll
        for (int r=0;r<4;r++)
          ph[fi][r] = sigmoidf_(acc[mi][fi][r] + bfv[fi]);
      #pragma unroll
      for (int r=0;r<4;r++){
        int row = row0 + wm*64 + mi*16 + (l>>4)*4 + r;
        #pragma unroll
        for (int fi=0;fi<4;fi++)
          outp[(size_t)row*256 + f0 + wf*64 + fi*16 + (l&15)] = f2bf(ph[fi][r]);
        // rowsum over this wave's 64 f-cols: butterfly within 16-lane group
        float s = ph[0][r]+ph[1][r]+ph[2][r]+ph[3][r];
        s += __shfl_xor(s,1); s += __shfl_xor(s,2); s += __shfl_xor(s,4); s += __shfl_xor(s,8);
        if ((l & 15) == 0) atomicAdd(&sums[row], s);
      }
    }
  } else {
    const int b = row0 >> 12;            // 4096 rows/batch, tiles never straddle
    float cpart[4] = {0.f,0.f,0.f,0.f};
    #pragma unroll
    for (int mi=0;mi<4;mi++) {
      #pragma unroll
      for (int fi=0;fi<4;fi++){
        #pragma unroll
        for (int r=0;r<4;r++){
          float ph = sigmoidf_(acc[mi][fi][r] + bfv[fi]);
          cpart[fi] += ph;
          int fl = wf*64 + fi*16 + (l&15);
          int nl = wm*64 + mi*16 + (l>>4)*4 + r;
          T_lds[fl*136 + nl] = f2bf(ph);
        }
      }
    }
    #pragma unroll
    for (int fi=0;fi<4;fi++){
      float s = cpart[fi];
      s += __shfl_xor(s,16); s += __shfl_xor(s,32);   // reduce over quads (rows)
      if (l < 16) atomicAdd(&sums[b*256 + f0 + wf*64 + fi*16 + l], s);
    }
    __syncthreads();
    const int frr = t >> 1, st = (t & 1)*64;
    size_t gbase = ((size_t)(b*256 + f0 + frr))*4096 + (row0 & 4095);
    #pragma unroll
    for (int j=0;j<8;j++)
      *(us8*)&outp[gbase + st + j*8] = *(const us8*)&T_lds[frr*136 + st + j*8];
  }
}

// ---------------------------------------------------------------------------
// KV partials: for (b, e-tile 64, n-chunk 512):
//  E[n,e] = exp(phi_k[n,e] * inv_cs[e] * V[n,e])   (bf16; denom accumulated f32)
//  parts[nc][b][d][e] = sum_n phi_kT[d][n] * E[n,e]   (unnormalized, split-N)
// Block: full d=256 x 64 e, 4 waves (64d x 64e each), BK=64 (2 mfma-K).
// ---------------------------------------------------------------------------
__global__ __launch_bounds__(256) void kv_kernel(const u16* __restrict__ phi_kT,
    const float* __restrict__ V, const float* __restrict__ colsum,
    float* __restrict__ parts, float* __restrict__ denom)
{
  __shared__ u16  phiT_lds[256][72];   // [d][n], stride 144 B (16B mult)
  __shared__ float V_lds[64][68];      // [n][e], float4-aligned stride
  __shared__ u16  E_lds[64][72];       // [e][n]

  const int t = threadIdx.x;
  const int l = t & 63;
  const int w = t >> 6;
  const int e0    = blockIdx.x * 64;   // 0..3
  const int nc    = blockIdx.y;        // 0..7
  const int b     = blockIdx.z;        // 0..15
  const int nbase = nc * 512;

  const int eown = t & 63;
  const int nq   = (t >> 6) * 16;
  const float inv_cs = 1.0f / (colsum[b*256 + e0 + eown] + EPS_);
  float dsum = 0.f;

  const int drow = t >> 3, oct = t & 7;   // phiT staging: 8 lanes/row (128B rows)
  const int vn = t >> 4, vq = t & 15;     // V staging: 16 lanes/row (256B rows)

  f32x4 acc[4][4];
  #pragma unroll
  for (int i=0;i<4;i++)
    #pragma unroll
    for (int j=0;j<4;j++) acc[i][j] = (f32x4){0.f,0.f,0.f,0.f};

  for (int c = 0; c < 8; c++) {
    const int n0 = nbase + c*64;
    #pragma unroll
    for (int p = 0; p < 8; p++) {
      int d = p*32 + drow;
      *(us8*)&phiT_lds[d][oct*8] =
        *(const us8*)&phi_kT[((size_t)(b*256 + d))*4096 + n0 + oct*8];
    }
    #pragma unroll
    for (int p = 0; p < 4; p++) {
      int n = p*16 + vn;
      *(float4*)&V_lds[n][vq*4] =
        *(const float4*)&V[((size_t)(b*4096 + n0 + n))*256 + e0 + vq*4];
    }
    __syncthreads();
    // E: thread owns (e = eown, n = nq..nq+15); phi e-rows already staged (e0+e < 256)
    #pragma unroll
    for (int jj = 0; jj < 2; jj++) {
      us8 pv = *(const us8*)&phiT_lds[e0 + eown][nq + jj*8];
      us8 ev;
      #pragma unroll
      for (int j = 0; j < 8; j++) {
        float ph = bf2f(pv[j]);
        float vv = V_lds[nq + jj*8 + j][eown];
        float ef = __expf(ph * inv_cs * vv);
        dsum += ef;
        ev[j] = f2bf(ef);
      }
      *(us8*)&E_lds[eown][nq + jj*8] = ev;
    }
    __syncthreads();
    #pragma unroll
    for (int kk = 0; kk < 2; kk++) {
      const int ko = kk*32 + (l>>4)*8;
      short8 af[4], bfr[4];
      #pragma unroll
      for (int mi=0;mi<4;mi++) af[mi]  = *(const short8*)&phiT_lds[w*64 + mi*16 + (l&15)][ko];
      #pragma unroll
      for (int ei=0;ei<4;ei++) bfr[ei] = *(const short8*)&E_lds[ei*16 + (l&15)][ko];
      #pragma unroll
      for (int mi=0;mi<4;mi++)
        #pragma unroll
        for (int ei=0;ei<4;ei++)
          acc[mi][ei] = __builtin_amdgcn_mfma_f32_16x16x32_bf16(af[mi], bfr[ei], acc[mi][ei],0,0,0);
    }
    __syncthreads();
  }

  atomicAdd(&denom[b*256 + e0 + eown], dsum);   // 4 threads per e

  float* slice = parts + ((size_t)(nc*16 + b)) * 65536;
  #pragma unroll
  for (int mi=0;mi<4;mi++)
    #pragma unroll
    for (int ei=0;ei<4;ei++)
      #pragma unroll
      for (int r=0;r<4;r++){
        int d = w*64 + mi*16 + (l>>4)*4 + r;
        int e = e0 + ei*16 + (l&15);
        slice[(size_t)d*256 + e] = acc[mi][ei][r];
      }
}

// ---------------------------------------------------------------------------
// KV_nT[b][e][d] = bf16( (sum_nc parts[nc][b][d][e]) / denom[b][e] )
// 64x64 LDS transpose per block.
// ---------------------------------------------------------------------------
__global__ __launch_bounds__(256) void kv_norm(const float* __restrict__ parts,
    const float* __restrict__ denom, u16* __restrict__ KV_nT)
{
  __shared__ float tile[64][65];
  const int t = threadIdx.x;
  const int d0 = blockIdx.x*64, e0 = blockIdx.y*64, b = blockIdx.z;
  const int i = t >> 4, jq = t & 15;
  #pragma unroll
  for (int p=0;p<4;p++){
    int dl = p*16 + i;
    float4 s = {0.f,0.f,0.f,0.f};
    for (int nc=0;nc<8;nc++){
      const float4 v = *(const float4*)&parts[(((size_t)(nc*16 + b))*256 + d0 + dl)*256 + e0 + jq*4];
      s.x+=v.x; s.y+=v.y; s.z+=v.z; s.w+=v.w;
    }
    tile[dl][jq*4+0]=s.x; tile[dl][jq*4+1]=s.y; tile[dl][jq*4+2]=s.z; tile[dl][jq*4+3]=s.w;
  }
  __syncthreads();
  const int el = t >> 4, dq = t & 15;
  #pragma unroll
  for (int p=0;p<4;p++){
    int e = p*16 + el;
    float dn = denom[b*256 + e0 + e];
    us4 o;
    #pragma unroll
    for (int r=0;r<4;r++) o[r] = f2bf(tile[dq*4+r][e] / dn);
    *(us4*)&KV_nT[((size_t)(b*256 + e0 + e))*256 + d0 + dq*4] = o;
  }
}

// ---------------------------------------------------------------------------
// out[b,n,e] = sigmoid(rs)/(rs+eps) * sum_d phi_q[n,d] * KV_n[d,e]
// Block tile 128n x 128e, 4 waves, BK=32. B-operand from KV_nT rows.
// ---------------------------------------------------------------------------
__global__ __launch_bounds__(256) void out_gemm(const u16* __restrict__ phi_q,
    const u16* __restrict__ KV_nT, const float* __restrict__ rowsum,
    float* __restrict__ outp)
{
  __shared__ u16 A_lds[128][40];
  __shared__ u16 B_lds[128][40];
  __shared__ float rs_lds[128];

  const int t = threadIdx.x;
  const int l = t & 63;
  const int w = t >> 6;
  const int wm = w & 1, we = w >> 1;
  const int n0 = blockIdx.x * 128;
  const int e0 = blockIdx.y * 128;
  const int b  = blockIdx.z;

  if (t < 128) rs_lds[t] = rowsum[b*4096 + n0 + t];

  f32x4 acc[4][4];
  #pragma unroll
  for (int i=0;i<4;i++)
    #pragma unroll
    for (int j=0;j<4;j++) acc[i][j] = (f32x4){0.f,0.f,0.f,0.f};

  const int nr4 = t >> 2, q4 = t & 3;   // 4 lanes/row, 64B per row-chunk
  const int kof = (l>>4)*8;

  for (int k0 = 0; k0 < 256; k0 += 32) {
    #pragma unroll
    for (int p=0;p<2;p++){
      int n = p*64 + nr4;
      *(us8*)&A_lds[n][q4*8] = *(const us8*)&phi_q[((size_t)(b*4096 + n0 + n))*256 + k0 + q4*8];
      *(us8*)&B_lds[n][q4*8] = *(const us8*)&KV_nT[((size_t)(b*256 + e0 + n))*256 + k0 + q4*8];
    }
    __syncthreads();
    short8 af[4], bfr[4];
    #pragma unroll
    for (int mi=0;mi<4;mi++) af[mi]  = *(const short8*)&A_lds[wm*64+mi*16+(l&15)][kof];
    #pragma unroll
    for (int ei=0;ei<4;ei++) bfr[ei] = *(const short8*)&B_lds[we*64+ei*16+(l&15)][kof];
    #pragma unroll
    for (int mi=0;mi<4;mi++)
      #pragma unroll
      for (int ei=0;ei<4;ei++)
        acc[mi][ei] = __builtin_amdgcn_mfma_f32_16x16x32_bf16(af[mi], bfr[ei], acc[mi][ei],0,0,0);
    __syncthreads();
  }

  #pragma unroll
  for (int mi=0;mi<4;mi++){
    #pragma unroll
    for (int r=0;r<4;r++){
      int nl = wm*64 + mi*16 + (l>>4)*4 + r;
      float rs = rs_lds[nl];
      float gate = sigmoidf_(rs) / (rs + EPS_);
      #pragma unroll
      for (int ei=0;ei<4;ei++)
        outp[((size_t)(b*4096 + n0 + nl))*256 + e0 + we*64 + ei*16 + (l&15)] = gate*acc[mi][ei][r];
    }
  }
}

extern "C" void kernel_launch(void* const* d_in, const int* in_sizes, int n_in,
                              void* d_out, int out_size, void* d_ws, size_t ws_size,
                              hipStream_t stream) {
  const float* Q  = (const float*)d_in[0];
  const float* K  = (const float*)d_in[1];
  const float* V  = (const float*)d_in[2];
  const float* Wq = (const float*)d_in[3];
  const float* bq = (const float*)d_in[4];
  const float* Wk = (const float*)d_in[5];
  const float* bk = (const float*)d_in[6];
  float* out = (float*)d_out;

  // workspace layout (103 MB total)
  u16* phi_q  = (u16*)d_ws;                 // 16,777,216 bf16
  u16* phi_kT = phi_q + 16777216;           // 16,777,216 bf16  [b][d][n]
  u16* WqT    = phi_kT + 16777216;          // 65,536
  u16* WkT    = WqT + 65536;                // 65,536
  float* colsum = (float*)(WkT + 65536);    // 4096
  float* denom  = colsum + 4096;            // 4096
  float* rowsum = denom + 4096;             // 65,536
  float* parts  = rowsum + 65536;           // 8*16*65536 f32 (33.5 MB)
  u16* KV_nT  = (u16*)(parts + 8388608);    // 1,048,576 bf16  [b][e][d]

  // zero atomic accumulators (colsum, denom, rowsum contiguous)
  hipMemsetAsync(colsum, 0, (4096 + 4096 + 65536) * sizeof(float), stream);

  prep_w<<<dim3(512), 256, 0, stream>>>(Wq, Wk, WqT, WkT);
  phi_gemm<false><<<dim3(512, 2), 256, 0, stream>>>(Q, WqT, bq, phi_q, rowsum);
  phi_gemm<true ><<<dim3(512, 2), 256, 0, stream>>>(K, WkT, bk, phi_kT, colsum);
  kv_kernel<<<dim3(4, 8, 16), 256, 0, stream>>>(phi_kT, V, colsum, parts, denom);
  kv_norm<<<dim3(4, 4, 16), 256, 0, stream>>>(parts, denom, KV_nT);
  out_gemm<<<dim3(32, 2, 16), 256, 0, stream>>>(phi_q, KV_nT, rowsum, out);
}